// Round 1
// baseline (1732.663 us; speedup 1.0000x reference)
//
#include <hip/hip_runtime.h>
#include <math.h>

constexpr int kD  = 1024;
constexpr int kNH = 16;
constexpr int kDH = 64;
constexpr int kB  = 2;
constexpr int kL  = 2048;
constexpr int kM  = kB * kL; // 4096 rows total

#define COMP(v, i) ((i)==0 ? (v).x : (i)==1 ? (v).y : (i)==2 ? (v).z : (v).w)

// ---------------- LayerNorm: one block (256 thr) per row ----------------
__global__ __launch_bounds__(256) void ln_kernel(
    const float* __restrict__ x, const float* __restrict__ g,
    const float* __restrict__ beta, float* __restrict__ h)
{
    const int row = blockIdx.x;
    const int tid = threadIdx.x;
    const float4 v = ((const float4*)(x + (size_t)row * kD))[tid];
    float s  = v.x + v.y + v.z + v.w;
    float s2 = v.x*v.x + v.y*v.y + v.z*v.z + v.w*v.w;
    #pragma unroll
    for (int off = 32; off > 0; off >>= 1) {
        s  += __shfl_down(s, off);
        s2 += __shfl_down(s2, off);
    }
    __shared__ float wsum[4], wsum2[4];
    const int lane = tid & 63, wid = tid >> 6;
    if (lane == 0) { wsum[wid] = s; wsum2[wid] = s2; }
    __syncthreads();
    const float ts   = wsum[0] + wsum[1] + wsum[2] + wsum[3];
    const float ts2  = wsum2[0] + wsum2[1] + wsum2[2] + wsum2[3];
    const float mean = ts * (1.0f / kD);
    const float var  = ts2 * (1.0f / kD) - mean * mean;
    const float rstd = rsqrtf(var + 1e-5f);
    const float4 gv = ((const float4*)g)[tid];
    const float4 bv = ((const float4*)beta)[tid];
    float4 o;
    o.x = (v.x - mean) * rstd * gv.x + bv.x;
    o.y = (v.y - mean) * rstd * gv.y + bv.y;
    o.z = (v.z - mean) * rstd * gv.z + bv.z;
    o.w = (v.w - mean) * rstd * gv.w + bv.w;
    ((float4*)(h + (size_t)row * kD))[tid] = o;
}

// ---------------- NT GEMM: C[M,N] = A[M,K] * Bw[N,K]^T + bias (+gelu(x+.)) ----
// 64x64 tile, BK=32, 256 threads, 4x4 micro-tile per thread.
template<bool FUSE_GELU>
__global__ __launch_bounds__(256) void gemm_nt(
    const float* __restrict__ A, const float* __restrict__ Bw,
    const float* __restrict__ bias, const float* __restrict__ resid,
    float* __restrict__ C, int N, int K)
{
    constexpr int BM = 64, BN = 64, BK = 32;
    __shared__ float As[BK][BM + 4];
    __shared__ float Bs[BK][BN + 4];
    const int tid = threadIdx.x;
    const int tx = tid & 15, ty = tid >> 4;
    const int row0 = blockIdx.y * BM;
    const int col0 = blockIdx.x * BN;
    float acc[4][4] = {};
    for (int k0 = 0; k0 < K; k0 += BK) {
        #pragma unroll
        for (int i = tid; i < BM * (BK/4); i += 256) {
            const int r = i >> 3, kq = (i & 7) * 4;
            const float4 a = *(const float4*)&A[(size_t)(row0 + r) * K + k0 + kq];
            As[kq+0][r] = a.x; As[kq+1][r] = a.y; As[kq+2][r] = a.z; As[kq+3][r] = a.w;
        }
        #pragma unroll
        for (int i = tid; i < BN * (BK/4); i += 256) {
            const int r = i >> 3, kq = (i & 7) * 4;
            const float4 b = *(const float4*)&Bw[(size_t)(col0 + r) * K + k0 + kq];
            Bs[kq+0][r] = b.x; Bs[kq+1][r] = b.y; Bs[kq+2][r] = b.z; Bs[kq+3][r] = b.w;
        }
        __syncthreads();
        #pragma unroll
        for (int k = 0; k < BK; ++k) {
            const float4 a4 = *(const float4*)&As[k][ty*4];
            const float4 b4 = *(const float4*)&Bs[k][tx*4];
            #pragma unroll
            for (int r = 0; r < 4; ++r)
                #pragma unroll
                for (int c = 0; c < 4; ++c)
                    acc[r][c] += COMP(a4, r) * COMP(b4, c);
        }
        __syncthreads();
    }
    const float4 bv = *(const float4*)&bias[col0 + tx*4];
    #pragma unroll
    for (int r = 0; r < 4; ++r) {
        const int gr = row0 + ty*4 + r;
        float4 o;
        o.x = acc[r][0] + bv.x; o.y = acc[r][1] + bv.y;
        o.z = acc[r][2] + bv.z; o.w = acc[r][3] + bv.w;
        if (FUSE_GELU) {
            const float4 res = *(const float4*)&resid[(size_t)gr * N + col0 + tx*4];
            o.x += res.x; o.y += res.y; o.z += res.z; o.w += res.w;
            o.x = 0.5f * o.x * (1.0f + erff(o.x * 0.70710678118654752f));
            o.y = 0.5f * o.y * (1.0f + erff(o.y * 0.70710678118654752f));
            o.z = 0.5f * o.z * (1.0f + erff(o.z * 0.70710678118654752f));
            o.w = 0.5f * o.w * (1.0f + erff(o.w * 0.70710678118654752f));
        }
        *(float4*)&C[(size_t)gr * N + col0 + tx*4] = o;
    }
}

// ---------------- Flash-style causal attention ----------------
// grid.x = q-tile (64 rows), grid.y = b*NH + h. 256 threads, 4x4 micro-tiles.
__global__ __launch_bounds__(256) void attn_kernel(
    const float* __restrict__ proj, const float* __restrict__ mask,
    float* __restrict__ heads)
{
    __shared__ float Qs[64][68], Ks[64][68], Vs[64][68], Ps[64][68];
    __shared__ float m_arr[64], l_arr[64], alpha_arr[64];
    __shared__ float pmax[64][4], psum[64][4];
    const int tid = threadIdx.x;
    const int tx = tid & 15, ty = tid >> 4;
    const int bh = blockIdx.y;
    const int b = bh >> 4, hh = bh & 15;
    const int q0 = blockIdx.x * 64;
    const float inv_scale = 1.0f / 32.0f; // 1/sqrt(D)

    // load + prescale Q tile
    #pragma unroll
    for (int i = tid; i < 64 * 16; i += 256) {
        const int r = i >> 4, c4 = (i & 15) * 4;
        const float4 q = *(const float4*)&proj[((size_t)(b*kL + q0 + r)) * 3072 + hh*kDH + c4];
        Qs[r][c4+0] = q.x * inv_scale; Qs[r][c4+1] = q.y * inv_scale;
        Qs[r][c4+2] = q.z * inv_scale; Qs[r][c4+3] = q.w * inv_scale;
    }
    if (tid < 64) { m_arr[tid] = -INFINITY; l_arr[tid] = 0.0f; }
    float acc[4][4] = {};
    const int ntiles = blockIdx.x + 1; // causal: only k-tiles with j0 <= q0+63
    const int sr = tid & 63, seg = tid >> 6;

    for (int jt = 0; jt < ntiles; ++jt) {
        const int j0 = jt * 64;
        __syncthreads(); // protect Ks/Vs/Ps reuse; makes Q visible on first iter
        #pragma unroll
        for (int i = tid; i < 64 * 16; i += 256) {
            const int r = i >> 4, c4 = (i & 15) * 4;
            const size_t base = ((size_t)(b*kL + j0 + r)) * 3072 + hh*kDH + c4;
            const float4 kv = *(const float4*)&proj[base + 1024];
            Ks[r][c4+0]=kv.x; Ks[r][c4+1]=kv.y; Ks[r][c4+2]=kv.z; Ks[r][c4+3]=kv.w;
            const float4 vv = *(const float4*)&proj[base + 2048];
            Vs[r][c4+0]=vv.x; Vs[r][c4+1]=vv.y; Vs[r][c4+2]=vv.z; Vs[r][c4+3]=vv.w;
        }
        __syncthreads();
        // S = (Q/32) · K^T  (+ mask afterwards; exp underflow identical to ref)
        float s[4][4] = {};
        #pragma unroll
        for (int c4 = 0; c4 < 16; ++c4) {
            float4 qr[4], kr[4];
            #pragma unroll
            for (int r = 0; r < 4; ++r) qr[r] = *(const float4*)&Qs[ty*4 + r][c4*4];
            #pragma unroll
            for (int c = 0; c < 4; ++c) kr[c] = *(const float4*)&Ks[tx*4 + c][c4*4];
            #pragma unroll
            for (int r = 0; r < 4; ++r)
                #pragma unroll
                for (int c = 0; c < 4; ++c)
                    s[r][c] += qr[r].x*kr[c].x + qr[r].y*kr[c].y
                             + qr[r].z*kr[c].z + qr[r].w*kr[c].w;
        }
        #pragma unroll
        for (int r = 0; r < 4; ++r) {
            const int gq = q0 + ty*4 + r;
            #pragma unroll
            for (int c = 0; c < 4; ++c) {
                const float mv = mask[(size_t)gq * kL + j0 + tx*4 + c];
                Ps[ty*4 + r][tx*4 + c] = s[r][c] + mv;
            }
        }
        __syncthreads();
        // online softmax, 4 segments of 16 cols per row
        const float m_old = m_arr[sr];
        float pm = -INFINITY;
        #pragma unroll
        for (int c4 = 0; c4 < 4; ++c4) {
            const float4 p = *(const float4*)&Ps[sr][seg*16 + c4*4];
            pm = fmaxf(pm, fmaxf(fmaxf(p.x, p.y), fmaxf(p.z, p.w)));
        }
        pmax[sr][seg] = pm;
        __syncthreads();
        const float m_new = fmaxf(m_old,
            fmaxf(fmaxf(pmax[sr][0], pmax[sr][1]), fmaxf(pmax[sr][2], pmax[sr][3])));
        float psm = 0.0f;
        #pragma unroll
        for (int c4 = 0; c4 < 4; ++c4) {
            float4 p = *(const float4*)&Ps[sr][seg*16 + c4*4];
            p.x = expf(p.x - m_new); p.y = expf(p.y - m_new);
            p.z = expf(p.z - m_new); p.w = expf(p.w - m_new);
            psm += p.x + p.y + p.z + p.w;
            *(float4*)&Ps[sr][seg*16 + c4*4] = p;
        }
        psum[sr][seg] = psm;
        if (seg == 0) { alpha_arr[sr] = expf(m_old - m_new); m_arr[sr] = m_new; }
        __syncthreads();
        if (seg == 0)
            l_arr[sr] = l_arr[sr] * alpha_arr[sr]
                      + psum[sr][0] + psum[sr][1] + psum[sr][2] + psum[sr][3];
        // rescale accumulator, then O += P·V
        #pragma unroll
        for (int r = 0; r < 4; ++r) {
            const float a = alpha_arr[ty*4 + r];
            acc[r][0]*=a; acc[r][1]*=a; acc[r][2]*=a; acc[r][3]*=a;
        }
        #pragma unroll
        for (int j4 = 0; j4 < 16; ++j4) {
            float4 pr[4], vr[4];
            #pragma unroll
            for (int r = 0; r < 4; ++r) pr[r] = *(const float4*)&Ps[ty*4 + r][j4*4];
            #pragma unroll
            for (int jj = 0; jj < 4; ++jj) vr[jj] = *(const float4*)&Vs[j4*4 + jj][tx*4];
            #pragma unroll
            for (int r = 0; r < 4; ++r)
                #pragma unroll
                for (int c = 0; c < 4; ++c)
                    acc[r][c] += pr[r].x*COMP(vr[0],c) + pr[r].y*COMP(vr[1],c)
                               + pr[r].z*COMP(vr[2],c) + pr[r].w*COMP(vr[3],c);
        }
    }
    __syncthreads();
    #pragma unroll
    for (int r = 0; r < 4; ++r) {
        const float invl = 1.0f / l_arr[ty*4 + r];
        float4 o;
        o.x = acc[r][0]*invl; o.y = acc[r][1]*invl;
        o.z = acc[r][2]*invl; o.w = acc[r][3]*invl;
        *(float4*)&heads[((size_t)(b*kL + q0 + ty*4 + r)) * kD + hh*kDH + tx*4] = o;
    }
}

extern "C" void kernel_launch(void* const* d_in, const int* in_sizes, int n_in,
                              void* d_out, int out_size, void* d_ws, size_t ws_size,
                              hipStream_t stream)
{
    const float* x    = (const float*)d_in[0];
    const float* mask = (const float*)d_in[1];
    const float* wx_w = (const float*)d_in[2];
    const float* wx_b = (const float*)d_in[3];
    const float* wo_w = (const float*)d_in[4];
    const float* wo_b = (const float*)d_in[5];
    const float* ln_g = (const float*)d_in[6];
    const float* ln_b = (const float*)d_in[7];
    float* out = (float*)d_out;

    // workspace layout (fp32): h 16MB | proj 48MB | heads 16MB  => 80MB
    float* h     = (float*)d_ws;
    float* proj  = h + (size_t)kM * kD;
    float* heads = proj + (size_t)kM * 3 * kD;

    ln_kernel<<<kM, 256, 0, stream>>>(x, ln_g, ln_b, h);
    gemm_nt<false><<<dim3(3*kD/64, kM/64), 256, 0, stream>>>(
        h, wx_w, wx_b, nullptr, proj, 3*kD, kD);
    attn_kernel<<<dim3(kL/64, kB*kNH), 256, 0, stream>>>(proj, mask, heads);
    gemm_nt<true><<<dim3(kD/64, kM/64), 256, 0, stream>>>(
        heads, wo_w, wo_b, x, out, kD, kD);
    // second tuple output: pass-through mask
    hipMemcpyAsync(out + (size_t)kM * kD, mask, (size_t)kL * kL * sizeof(float),
                   hipMemcpyDeviceToDevice, stream);
}

// Round 2
// 1554.520 us; speedup vs baseline: 1.1146x; 1.1146x over previous
//
#include <hip/hip_runtime.h>
#include <math.h>

constexpr int kD  = 1024;
constexpr int kNH = 16;
constexpr int kB  = 2;
constexpr int kL  = 2048;
constexpr int kM  = kB * kL; // 4096 rows total

#define COMP(v, i) ((i)==0 ? (v).x : (i)==1 ? (v).y : (i)==2 ? (v).z : (v).w)

// ---------------- LayerNorm: one block (256 thr) per row ----------------
__global__ __launch_bounds__(256) void ln_kernel(
    const float* __restrict__ x, const float* __restrict__ g,
    const float* __restrict__ beta, float* __restrict__ h)
{
    const int row = blockIdx.x;
    const int tid = threadIdx.x;
    const float4 v = ((const float4*)(x + (size_t)row * kD))[tid];
    float s  = v.x + v.y + v.z + v.w;
    float s2 = v.x*v.x + v.y*v.y + v.z*v.z + v.w*v.w;
    #pragma unroll
    for (int off = 32; off > 0; off >>= 1) {
        s  += __shfl_down(s, off);
        s2 += __shfl_down(s2, off);
    }
    __shared__ float wsum[4], wsum2[4];
    const int lane = tid & 63, wid = tid >> 6;
    if (lane == 0) { wsum[wid] = s; wsum2[wid] = s2; }
    __syncthreads();
    const float ts   = wsum[0] + wsum[1] + wsum[2] + wsum[3];
    const float ts2  = wsum2[0] + wsum2[1] + wsum2[2] + wsum2[3];
    const float mean = ts * (1.0f / kD);
    const float var  = ts2 * (1.0f / kD) - mean * mean;
    const float rstd = rsqrtf(var + 1e-5f);
    const float4 gv = ((const float4*)g)[tid];
    const float4 bv = ((const float4*)beta)[tid];
    float4 o;
    o.x = (v.x - mean) * rstd * gv.x + bv.x;
    o.y = (v.y - mean) * rstd * gv.y + bv.y;
    o.z = (v.z - mean) * rstd * gv.z + bv.z;
    o.w = (v.w - mean) * rstd * gv.w + bv.w;
    ((float4*)(h + (size_t)row * kD))[tid] = o;
}

// ---------------- NT GEMM: C[M,N] = A[M,K] * Bw[N,K]^T + bias (+gelu(x+.)) ----
// 128x128 tile, BK=32, 256 threads, 8x8 micro-tile (split-halves), LDS transposed.
template<bool FUSE_GELU>
__global__ __launch_bounds__(256) void gemm_nt(
    const float* __restrict__ A, const float* __restrict__ Bw,
    const float* __restrict__ bias, const float* __restrict__ resid,
    float* __restrict__ C, int N, int K)
{
    constexpr int BM = 128, BN = 128, BK = 32;
    __shared__ float AT[BK][132];  // AT[k][m], 132 stride: even bank spread
    __shared__ float BT[BK][132];  // BT[k][n]
    const int tid = threadIdx.x;
    const int tx = tid & 15, ty = tid >> 4;
    const int row0 = blockIdx.y * BM;
    const int col0 = blockIdx.x * BN;
    float acc[2][2][4][4] = {};
    for (int k0 = 0; k0 < K; k0 += BK) {
        __syncthreads();
        #pragma unroll
        for (int i = tid; i < BM * (BK/4); i += 256) {   // 4 iters
            const int r = i >> 3, c4 = (i & 7) * 4;
            const float4 a = *(const float4*)&A[(size_t)(row0 + r) * K + k0 + c4];
            AT[c4+0][r] = a.x; AT[c4+1][r] = a.y; AT[c4+2][r] = a.z; AT[c4+3][r] = a.w;
        }
        #pragma unroll
        for (int i = tid; i < BN * (BK/4); i += 256) {
            const int r = i >> 3, c4 = (i & 7) * 4;
            const float4 bq = *(const float4*)&Bw[(size_t)(col0 + r) * K + k0 + c4];
            BT[c4+0][r] = bq.x; BT[c4+1][r] = bq.y; BT[c4+2][r] = bq.z; BT[c4+3][r] = bq.w;
        }
        __syncthreads();
        #pragma unroll
        for (int k = 0; k < BK; ++k) {
            float4 a4[2], b4[2];
            a4[0] = *(const float4*)&AT[k][ty*4];
            a4[1] = *(const float4*)&AT[k][64 + ty*4];
            b4[0] = *(const float4*)&BT[k][tx*4];
            b4[1] = *(const float4*)&BT[k][64 + tx*4];
            #pragma unroll
            for (int hm = 0; hm < 2; ++hm)
                #pragma unroll
                for (int hn = 0; hn < 2; ++hn)
                    #pragma unroll
                    for (int r = 0; r < 4; ++r)
                        #pragma unroll
                        for (int c = 0; c < 4; ++c)
                            acc[hm][hn][r][c] += COMP(a4[hm], r) * COMP(b4[hn], c);
        }
    }
    float4 bv[2];
    bv[0] = *(const float4*)&bias[col0 + tx*4];
    bv[1] = *(const float4*)&bias[col0 + 64 + tx*4];
    #pragma unroll
    for (int hm = 0; hm < 2; ++hm)
        #pragma unroll
        for (int r = 0; r < 4; ++r) {
            const int gr = row0 + hm*64 + ty*4 + r;
            #pragma unroll
            for (int hn = 0; hn < 2; ++hn) {
                const int gc = col0 + hn*64 + tx*4;
                float4 o;
                o.x = acc[hm][hn][r][0] + bv[hn].x;
                o.y = acc[hm][hn][r][1] + bv[hn].y;
                o.z = acc[hm][hn][r][2] + bv[hn].z;
                o.w = acc[hm][hn][r][3] + bv[hn].w;
                if (FUSE_GELU) {
                    const float4 res = *(const float4*)&resid[(size_t)gr * N + gc];
                    o.x += res.x; o.y += res.y; o.z += res.z; o.w += res.w;
                    o.x = 0.5f * o.x * (1.0f + erff(o.x * 0.70710678118654752f));
                    o.y = 0.5f * o.y * (1.0f + erff(o.y * 0.70710678118654752f));
                    o.z = 0.5f * o.z * (1.0f + erff(o.z * 0.70710678118654752f));
                    o.w = 0.5f * o.w * (1.0f + erff(o.w * 0.70710678118654752f));
                }
                *(float4*)&C[(size_t)gr * N + gc] = o;
            }
        }
}

// ---------------- Flash-style causal attention, wave-private softmax --------
// grid.x = q-tile (64 rows), grid.y = b*NH + h. 256 threads = 4 waves;
// wave w owns q-rows [w*16, w*16+16). Per thread: 4 q-rows (ty2) x 4 cols (tx).
__global__ __launch_bounds__(256) void attn_kernel(
    const float* __restrict__ proj, float* __restrict__ heads)
{
    __shared__ float Qs[64][68];      // row-major, broadcast reads
    __shared__ float KT[64][65];      // KT[k][j]: transposed K tile
    __shared__ float Vs[64][68];      // row-major V tile
    __shared__ float Ps[4][16][68];   // wave-private P slabs
    const int tid  = threadIdx.x;
    const int lane = tid & 63;
    const int w    = tid >> 6;        // wave 0..3
    const int tx   = lane & 15;       // col group (4 cols)
    const int ty2  = lane >> 4;       // row group within wave (4 rows)
    const int bh = blockIdx.y;
    const int b = bh >> 4, hh = bh & 15;
    const int q0 = blockIdx.x * 64;
    const int qrow = w*16 + ty2*4;    // local base of this thread's 4 q rows
    const float inv_scale = 1.0f / 32.0f; // 1/sqrt(D)

    // load + prescale Q tile (row-major)
    #pragma unroll
    for (int i = tid; i < 64 * 16; i += 256) {
        const int r = i >> 4, c4 = (i & 15) * 4;
        const float4 q = *(const float4*)&proj[((size_t)(b*kL + q0 + r)) * 3072 + hh*64 + c4];
        Qs[r][c4+0] = q.x * inv_scale; Qs[r][c4+1] = q.y * inv_scale;
        Qs[r][c4+2] = q.z * inv_scale; Qs[r][c4+3] = q.w * inv_scale;
    }
    float m_row[4], l_row[4];
    #pragma unroll
    for (int r = 0; r < 4; ++r) { m_row[r] = -INFINITY; l_row[r] = 0.0f; }
    float acc[4][4] = {};
    const int ntiles = blockIdx.x + 1;  // causal tile skipping

    for (int jt = 0; jt < ntiles; ++jt) {
        const int j0 = jt * 64;
        __syncthreads();  // everyone done with previous KT/Vs (and Qs visible, iter 0)
        #pragma unroll
        for (int i = tid; i < 64 * 16; i += 256) {
            const int r = i >> 4, c4 = (i & 15) * 4;
            const size_t base = ((size_t)(b*kL + j0 + r)) * 3072 + hh*64 + c4;
            const float4 kv = *(const float4*)&proj[base + 1024];
            KT[c4+0][r] = kv.x; KT[c4+1][r] = kv.y; KT[c4+2][r] = kv.z; KT[c4+3][r] = kv.w;
            const float4 vv = *(const float4*)&proj[base + 2048];
            *(float4*)&Vs[r][c4] = vv;
        }
        __syncthreads();

        // S[r][c] = sum_k Q[qrow+r][k] * KT[k][tx*4+c]  (outer-product over k)
        float s[4][4] = {};
        #pragma unroll
        for (int k4 = 0; k4 < 16; ++k4) {
            float4 q4[4], kt[4];
            #pragma unroll
            for (int r = 0; r < 4; ++r) q4[r] = *(const float4*)&Qs[qrow + r][k4*4];
            #pragma unroll
            for (int kk = 0; kk < 4; ++kk) kt[kk] = *(const float4*)&KT[k4*4 + kk][tx*4];
            #pragma unroll
            for (int r = 0; r < 4; ++r)
                #pragma unroll
                for (int kk = 0; kk < 4; ++kk) {
                    const float qv = COMP(q4[r], kk);
                    s[r][0] += qv * kt[kk].x; s[r][1] += qv * kt[kk].y;
                    s[r][2] += qv * kt[kk].z; s[r][3] += qv * kt[kk].w;
                }
        }
        // causal mask, arithmetic, diagonal tile only (j global > q global)
        if (jt == blockIdx.x) {
            #pragma unroll
            for (int r = 0; r < 4; ++r)
                #pragma unroll
                for (int c = 0; c < 4; ++c)
                    if (tx*4 + c > qrow + r) s[r][c] += -1e9f;
        }
        // wave-private online softmax (reduce over the 16 tx lanes)
        #pragma unroll
        for (int r = 0; r < 4; ++r) {
            float pm = fmaxf(fmaxf(s[r][0], s[r][1]), fmaxf(s[r][2], s[r][3]));
            pm = fmaxf(pm, __shfl_xor(pm, 1));
            pm = fmaxf(pm, __shfl_xor(pm, 2));
            pm = fmaxf(pm, __shfl_xor(pm, 4));
            pm = fmaxf(pm, __shfl_xor(pm, 8));
            const float m_new = fmaxf(m_row[r], pm);
            const float al = expf(m_row[r] - m_new);
            m_row[r] = m_new;
            float ps = 0.0f;
            #pragma unroll
            for (int c = 0; c < 4; ++c) {
                s[r][c] = expf(s[r][c] - m_new);
                ps += s[r][c];
            }
            ps += __shfl_xor(ps, 1);
            ps += __shfl_xor(ps, 2);
            ps += __shfl_xor(ps, 4);
            ps += __shfl_xor(ps, 8);
            l_row[r] = l_row[r] * al + ps;
            acc[r][0] *= al; acc[r][1] *= al; acc[r][2] *= al; acc[r][3] *= al;
        }
        // stash P in wave-private LDS slab (no cross-wave barrier needed)
        #pragma unroll
        for (int r = 0; r < 4; ++r) {
            float4 p; p.x = s[r][0]; p.y = s[r][1]; p.z = s[r][2]; p.w = s[r][3];
            *(float4*)&Ps[w][ty2*4 + r][tx*4] = p;
        }
        asm volatile("s_waitcnt lgkmcnt(0)" ::: "memory"); // writes visible before reads
        // O += P * V
        #pragma unroll
        for (int j4 = 0; j4 < 16; ++j4) {
            float4 p4[4], v4[4];
            #pragma unroll
            for (int r = 0; r < 4; ++r) p4[r] = *(const float4*)&Ps[w][ty2*4 + r][j4*4];
            #pragma unroll
            for (int jj = 0; jj < 4; ++jj) v4[jj] = *(const float4*)&Vs[j4*4 + jj][tx*4];
            #pragma unroll
            for (int r = 0; r < 4; ++r)
                #pragma unroll
                for (int jj = 0; jj < 4; ++jj) {
                    const float pv = COMP(p4[r], jj);
                    acc[r][0] += pv * v4[jj].x; acc[r][1] += pv * v4[jj].y;
                    acc[r][2] += pv * v4[jj].z; acc[r][3] += pv * v4[jj].w;
                }
        }
    }
    #pragma unroll
    for (int r = 0; r < 4; ++r) {
        const float invl = 1.0f / l_row[r];
        float4 o;
        o.x = acc[r][0]*invl; o.y = acc[r][1]*invl;
        o.z = acc[r][2]*invl; o.w = acc[r][3]*invl;
        *(float4*)&heads[((size_t)(b*kL + q0 + qrow + r)) * kD + hh*64 + tx*4] = o;
    }
}

extern "C" void kernel_launch(void* const* d_in, const int* in_sizes, int n_in,
                              void* d_out, int out_size, void* d_ws, size_t ws_size,
                              hipStream_t stream)
{
    const float* x    = (const float*)d_in[0];
    const float* mask = (const float*)d_in[1];
    const float* wx_w = (const float*)d_in[2];
    const float* wx_b = (const float*)d_in[3];
    const float* wo_w = (const float*)d_in[4];
    const float* wo_b = (const float*)d_in[5];
    const float* ln_g = (const float*)d_in[6];
    const float* ln_b = (const float*)d_in[7];
    float* out = (float*)d_out;

    // workspace layout (fp32): h 16MB | proj 48MB | heads 16MB  => 80MB
    float* h     = (float*)d_ws;
    float* proj  = h + (size_t)kM * kD;
    float* heads = proj + (size_t)kM * 3 * kD;

    ln_kernel<<<kM, 256, 0, stream>>>(x, ln_g, ln_b, h);
    gemm_nt<false><<<dim3(3*kD/128, kM/128), 256, 0, stream>>>(
        h, wx_w, wx_b, nullptr, proj, 3*kD, kD);
    attn_kernel<<<dim3(kL/64, kB*kNH), 256, 0, stream>>>(proj, heads);
    gemm_nt<true><<<dim3(kD/128, kM/128), 256, 0, stream>>>(
        heads, wo_w, wo_b, x, out, kD, kD);
    // second tuple output: pass-through mask
    hipMemcpyAsync(out + (size_t)kM * kD, mask, (size_t)kL * kL * sizeof(float),
                   hipMemcpyDeviceToDevice, stream);
}

// Round 4
// 512.070 us; speedup vs baseline: 3.3836x; 3.0358x over previous
//
#include <hip/hip_runtime.h>
#include <hip/hip_bf16.h>
#include <math.h>

constexpr int kD  = 1024;
constexpr int kB  = 2;
constexpr int kL  = 2048;
constexpr int kM  = kB * kL; // 4096 rows total

typedef __attribute__((ext_vector_type(8))) short  bf8v;   // 8 bf16 (4 VGPR) MFMA frag
typedef __attribute__((ext_vector_type(4))) float  f4v;    // MFMA accumulator
typedef __attribute__((ext_vector_type(4))) unsigned short us4v;

#define MFMA_BF16 __builtin_amdgcn_mfma_f32_16x16x32_bf16

__device__ inline unsigned short f2bf(float f) {
    __hip_bfloat16 h = __float2bfloat16(f);
    return *(unsigned short*)&h;
}
__device__ inline float bf2f(unsigned short u) {
    __hip_bfloat16 h = *(__hip_bfloat16*)&u;
    return __bfloat162float(h);
}

// ---------------- split-convert: fp32 -> (hi, lo) bf16 ----------------
__global__ __launch_bounds__(256) void convert_split(
    const float* __restrict__ src, unsigned short* __restrict__ hi,
    unsigned short* __restrict__ lo, int n4)
{
    const int i = blockIdx.x * 256 + threadIdx.x;
    if (i >= n4) return;
    const float4 v = ((const float4*)src)[i];
    const float vv[4] = {v.x, v.y, v.z, v.w};
    us4v h, l;
    #pragma unroll
    for (int c = 0; c < 4; ++c) {
        h[c] = f2bf(vv[c]);
        l[c] = f2bf(vv[c] - bf2f(h[c]));
    }
    *(us4v*)&hi[(size_t)i * 4] = h;
    *(us4v*)&lo[(size_t)i * 4] = l;
}

// ---------------- LayerNorm -> split bf16 ----------------
__global__ __launch_bounds__(256) void ln_kernel(
    const float* __restrict__ x, const float* __restrict__ g,
    const float* __restrict__ beta, unsigned short* __restrict__ h_hi,
    unsigned short* __restrict__ h_lo)
{
    const int row = blockIdx.x;
    const int tid = threadIdx.x;
    const float4 v = ((const float4*)(x + (size_t)row * kD))[tid];
    float s  = v.x + v.y + v.z + v.w;
    float s2 = v.x*v.x + v.y*v.y + v.z*v.z + v.w*v.w;
    #pragma unroll
    for (int off = 32; off > 0; off >>= 1) {
        s  += __shfl_down(s, off);
        s2 += __shfl_down(s2, off);
    }
    __shared__ float wsum[4], wsum2[4];
    const int lane = tid & 63, wid = tid >> 6;
    if (lane == 0) { wsum[wid] = s; wsum2[wid] = s2; }
    __syncthreads();
    const float ts   = wsum[0] + wsum[1] + wsum[2] + wsum[3];
    const float ts2  = wsum2[0] + wsum2[1] + wsum2[2] + wsum2[3];
    const float mean = ts * (1.0f / kD);
    const float var  = ts2 * (1.0f / kD) - mean * mean;
    const float rstd = rsqrtf(var + 1e-5f);
    const float4 gv = ((const float4*)g)[tid];
    const float4 bv = ((const float4*)beta)[tid];
    float o[4];
    o[0] = (v.x - mean) * rstd * gv.x + bv.x;
    o[1] = (v.y - mean) * rstd * gv.y + bv.y;
    o[2] = (v.z - mean) * rstd * gv.z + bv.z;
    o[3] = (v.w - mean) * rstd * gv.w + bv.w;
    us4v h, l;
    #pragma unroll
    for (int c = 0; c < 4; ++c) {
        h[c] = f2bf(o[c]);
        l[c] = f2bf(o[c] - bf2f(h[c]));
    }
    *(us4v*)&h_hi[(size_t)row * kD + tid * 4] = h;
    *(us4v*)&h_lo[(size_t)row * kD + tid * 4] = l;
}

// ---------------- split-bf16 MFMA NT GEMM ----------------
// C = (Ahi+Alo)[M,K] * (Bhi+Blo)[N,K]^T, acc = hh + hl + lh (3 MFMA).
// 128x128 tile, BK=32, 256 thr = 4 waves, each wave a 64x64 quadrant.
// MODE 0: out bf16 (proj) = acc + bias.  MODE 1: out fp32 = gelu(resid + acc + bias).
template<int MODE>
__global__ __launch_bounds__(256) void gemm_split(
    const unsigned short* __restrict__ Ahi, const unsigned short* __restrict__ Alo,
    const unsigned short* __restrict__ Bhi, const unsigned short* __restrict__ Blo,
    const float* __restrict__ bias, const float* __restrict__ resid,
    void* __restrict__ Cout, int N, int K)
{
    constexpr int BK = 32, PAD = 40;
    __shared__ unsigned short As[2][128][PAD];
    __shared__ unsigned short Bs[2][128][PAD];
    const int tid = threadIdx.x;
    const int l = tid & 63, w = tid >> 6;
    const int col16 = l & 15, grp = l >> 4;
    const int wr = (w >> 1) * 64, wc = (w & 1) * 64;
    const int row0 = blockIdx.y * 128, col0 = blockIdx.x * 128;
    f4v acc[4][4] = {};

    for (int k0 = 0; k0 < K; k0 += BK) {
        __syncthreads();
        #pragma unroll
        for (int t = 0; t < 2; ++t) {
            const int i = tid + t * 256;          // 512 slots of 8 elems
            const int r = i >> 2, c8 = (i & 3) * 8;
            const size_t ga = (size_t)(row0 + r) * K + k0 + c8;
            const size_t gb = (size_t)(col0 + r) * K + k0 + c8;
            *(bf8v*)&As[0][r][c8] = *(const bf8v*)&Ahi[ga];
            *(bf8v*)&As[1][r][c8] = *(const bf8v*)&Alo[ga];
            *(bf8v*)&Bs[0][r][c8] = *(const bf8v*)&Bhi[gb];
            *(bf8v*)&Bs[1][r][c8] = *(const bf8v*)&Blo[gb];
        }
        __syncthreads();
        bf8v ah[4], al[4], bh[4], bl[4];
        #pragma unroll
        for (int mi = 0; mi < 4; ++mi) {
            ah[mi] = *(bf8v*)&As[0][wr + mi*16 + col16][grp * 8];
            al[mi] = *(bf8v*)&As[1][wr + mi*16 + col16][grp * 8];
        }
        #pragma unroll
        for (int ni = 0; ni < 4; ++ni) {
            bh[ni] = *(bf8v*)&Bs[0][wc + ni*16 + col16][grp * 8];
            bl[ni] = *(bf8v*)&Bs[1][wc + ni*16 + col16][grp * 8];
        }
        #pragma unroll
        for (int mi = 0; mi < 4; ++mi)
            #pragma unroll
            for (int ni = 0; ni < 4; ++ni) {
                acc[mi][ni] = MFMA_BF16(ah[mi], bh[ni], acc[mi][ni], 0, 0, 0);
                acc[mi][ni] = MFMA_BF16(ah[mi], bl[ni], acc[mi][ni], 0, 0, 0);
                acc[mi][ni] = MFMA_BF16(al[mi], bh[ni], acc[mi][ni], 0, 0, 0);
            }
    }
    // epilogue: C[row0+wr+mi*16+grp*4+rr][col0+wc+ni*16+col16]
    #pragma unroll
    for (int mi = 0; mi < 4; ++mi)
        #pragma unroll
        for (int ni = 0; ni < 4; ++ni) {
            const int gcol = col0 + wc + ni*16 + col16;
            const float bb = bias[gcol];
            #pragma unroll
            for (int rr = 0; rr < 4; ++rr) {
                const int grow = row0 + wr + mi*16 + grp*4 + rr;
                float o = acc[mi][ni][rr] + bb;
                if (MODE == 0) {
                    ((unsigned short*)Cout)[(size_t)grow * N + gcol] = f2bf(o);
                } else {
                    o += resid[(size_t)grow * N + gcol];
                    o = 0.5f * o * (1.0f + erff(o * 0.70710678118654752f));
                    ((float*)Cout)[(size_t)grow * N + gcol] = o;
                }
            }
        }
}

// ---------------- MFMA flash attention (bf16 QK^T, split-bf16 PV) ----------
// grid = (L/64, B*NH). 256 thr = 4 waves; wave w owns q-rows [w*16, w*16+16).
// Writes heads as split bf16 (hi/lo) for the WO GEMM.
__global__ __launch_bounds__(256) void attn_mfma(
    const unsigned short* __restrict__ projb,
    unsigned short* __restrict__ heads_hi, unsigned short* __restrict__ heads_lo)
{
    __shared__ unsigned short Qs[64][72], Ks[64][72], Vt[64][72];
    __shared__ unsigned short Ps[4][16][72], Pl[4][16][72];
    const int tid = threadIdx.x;
    const int l = tid & 63, w = tid >> 6;
    const int col16 = l & 15, grp = l >> 4;
    const int bh = blockIdx.y, b = bh >> 4, hh = bh & 15;
    const int q0 = blockIdx.x * 64;

    // stage Q (row-major bf16)
    #pragma unroll
    for (int t = 0; t < 2; ++t) {
        const int i = tid + t * 256;
        const int r = i >> 3, c8 = (i & 7) * 8;
        *(bf8v*)&Qs[r][c8] =
            *(const bf8v*)&projb[(size_t)(b*kL + q0 + r) * 3072 + hh*64 + c8];
    }
    f4v accO[4] = {};
    float m_r[4], l_r[4];
    #pragma unroll
    for (int r = 0; r < 4; ++r) { m_r[r] = -INFINITY; l_r[r] = 0.0f; }
    const int ntiles = blockIdx.x + 1;

    for (int jt = 0; jt < ntiles; ++jt) {
        const int j0 = jt * 64;
        __syncthreads();   // prev tile done with Ks/Vt; Qs visible on iter 0
        #pragma unroll
        for (int t = 0; t < 2; ++t) {
            const int i = tid + t * 256;
            const int r = i >> 3, c8 = (i & 7) * 8;
            const size_t base = (size_t)(b*kL + j0 + r) * 3072 + hh*64 + c8;
            *(bf8v*)&Ks[r][c8] = *(const bf8v*)&projb[base + 1024];
            const bf8v vv = *(const bf8v*)&projb[base + 2048];
            #pragma unroll
            for (int q = 0; q < 8; ++q)
                Vt[c8 + q][r] = ((const unsigned short*)&vv)[q];  // transpose V
        }
        __syncthreads();

        // S = Q K^T  (A frag: row = lane&15, k = (lane>>4)*8; 2 k-steps of 32)
        f4v accS[4] = {};
        #pragma unroll
        for (int kk = 0; kk < 2; ++kk) {
            const bf8v aq = *(bf8v*)&Qs[w*16 + col16][grp*8 + kk*32];
            #pragma unroll
            for (int nj = 0; nj < 4; ++nj) {
                const bf8v bk = *(bf8v*)&Ks[nj*16 + col16][grp*8 + kk*32];
                accS[nj] = MFMA_BF16(aq, bk, accS[nj], 0, 0, 0);
            }
        }
        // scale + causal mask + wave-private online softmax
        const bool diag = (jt == blockIdx.x);
        float p[4][4];  // [nj][r]
        float alpha[4];
        #pragma unroll
        for (int r = 0; r < 4; ++r) {
            const int q_local = w*16 + grp*4 + r;
            float sv[4];
            #pragma unroll
            for (int nj = 0; nj < 4; ++nj) {
                sv[nj] = accS[nj][r] * (1.0f / 32.0f);
                if (diag && (nj*16 + col16 > q_local)) sv[nj] = -3.125e7f; // (-1e9)/32
            }
            float pm = fmaxf(fmaxf(sv[0], sv[1]), fmaxf(sv[2], sv[3]));
            pm = fmaxf(pm, __shfl_xor(pm, 1));
            pm = fmaxf(pm, __shfl_xor(pm, 2));
            pm = fmaxf(pm, __shfl_xor(pm, 4));
            pm = fmaxf(pm, __shfl_xor(pm, 8));
            const float m_new = fmaxf(m_r[r], pm);
            alpha[r] = expf(m_r[r] - m_new);
            m_r[r] = m_new;
            float ps = 0.0f;
            #pragma unroll
            for (int nj = 0; nj < 4; ++nj) {
                p[nj][r] = expf(sv[nj] - m_new);
                ps += p[nj][r];
            }
            ps += __shfl_xor(ps, 1);
            ps += __shfl_xor(ps, 2);
            ps += __shfl_xor(ps, 4);
            ps += __shfl_xor(ps, 8);
            l_r[r] = l_r[r] * alpha[r] + ps;
        }
        #pragma unroll
        for (int nd = 0; nd < 4; ++nd)
            #pragma unroll
            for (int r = 0; r < 4; ++r)
                accO[nd][r] *= alpha[r];
        // P -> wave-private LDS as hi/lo split (C-layout rows -> A-layout rows)
        #pragma unroll
        for (int nj = 0; nj < 4; ++nj)
            #pragma unroll
            for (int r = 0; r < 4; ++r) {
                const unsigned short hi = f2bf(p[nj][r]);
                Ps[w][grp*4 + r][nj*16 + col16] = hi;
                Pl[w][grp*4 + r][nj*16 + col16] = f2bf(p[nj][r] - bf2f(hi));
            }
        asm volatile("s_waitcnt lgkmcnt(0)" ::: "memory");
        // O += (Phi + Plo) V   (A = P[16q x 32j], B = V via Vt; 2 j-steps)
        #pragma unroll
        for (int js = 0; js < 2; ++js) {
            const bf8v ap = *(bf8v*)&Ps[w][col16][grp*8 + js*32];
            const bf8v al = *(bf8v*)&Pl[w][col16][grp*8 + js*32];
            #pragma unroll
            for (int nd = 0; nd < 4; ++nd) {
                const bf8v bv = *(bf8v*)&Vt[nd*16 + col16][grp*8 + js*32];
                accO[nd] = MFMA_BF16(ap, bv, accO[nd], 0, 0, 0);
                accO[nd] = MFMA_BF16(al, bv, accO[nd], 0, 0, 0);
            }
        }
    }
    // epilogue: heads split bf16
    #pragma unroll
    for (int nd = 0; nd < 4; ++nd)
        #pragma unroll
        for (int r = 0; r < 4; ++r) {
            const float o = accO[nd][r] / l_r[r];
            const unsigned short hi = f2bf(o);
            const unsigned short lo = f2bf(o - bf2f(hi));
            const size_t idx = (size_t)(b*kL + q0 + w*16 + grp*4 + r) * kD
                             + hh*64 + nd*16 + col16;
            heads_hi[idx] = hi;
            heads_lo[idx] = lo;
        }
}

extern "C" void kernel_launch(void* const* d_in, const int* in_sizes, int n_in,
                              void* d_out, int out_size, void* d_ws, size_t ws_size,
                              hipStream_t stream)
{
    const float* x    = (const float*)d_in[0];
    const float* mask = (const float*)d_in[1];
    const float* wx_w = (const float*)d_in[2];
    const float* wx_b = (const float*)d_in[3];
    const float* wo_w = (const float*)d_in[4];
    const float* wo_b = (const float*)d_in[5];
    const float* ln_g = (const float*)d_in[6];
    const float* ln_b = (const float*)d_in[7];
    float* out = (float*)d_out;

    // ws layout (bf16 ushort arrays):
    // h_hi 8MB | h_lo 8MB | wxhi 6 | wxlo 6 | wohi 2 | wolo 2 | projb 24 | hd_hi 8 | hd_lo 8  = 72MB
    unsigned short* h_hi  = (unsigned short*)d_ws;
    unsigned short* h_lo  = h_hi  + (size_t)kM * kD;
    unsigned short* wxhi  = h_lo  + (size_t)kM * kD;
    unsigned short* wxlo  = wxhi  + (size_t)3 * kD * kD;
    unsigned short* wohi  = wxlo  + (size_t)3 * kD * kD;
    unsigned short* wolo  = wohi  + (size_t)kD * kD;
    unsigned short* projb = wolo  + (size_t)kD * kD;
    unsigned short* hd_hi = projb + (size_t)kM * 3 * kD;
    unsigned short* hd_lo = hd_hi + (size_t)kM * kD;

    convert_split<<<(3*kD*kD/4 + 255)/256, 256, 0, stream>>>(wx_w, wxhi, wxlo, 3*kD*kD/4);
    convert_split<<<(kD*kD/4 + 255)/256, 256, 0, stream>>>(wo_w, wohi, wolo, kD*kD/4);
    ln_kernel<<<kM, 256, 0, stream>>>(x, ln_g, ln_b, h_hi, h_lo);
    gemm_split<0><<<dim3(3*kD/128, kM/128), 256, 0, stream>>>(
        h_hi, h_lo, wxhi, wxlo, wx_b, nullptr, projb, 3*kD, kD);
    attn_mfma<<<dim3(kL/64, kB*16), 256, 0, stream>>>(projb, hd_hi, hd_lo);
    gemm_split<1><<<dim3(kD/128, kM/128), 256, 0, stream>>>(
        hd_hi, hd_lo, wohi, wolo, wo_b, x, out, kD, kD);
    hipMemcpyAsync(out + (size_t)kM * kD, mask, (size_t)kL * kL * sizeof(float),
                   hipMemcpyDeviceToDevice, stream);
}

// Round 5
// 364.309 us; speedup vs baseline: 4.7560x; 1.4056x over previous
//
#include <hip/hip_runtime.h>
#include <hip/hip_bf16.h>
#include <math.h>

constexpr int kD  = 1024;
constexpr int kB  = 2;
constexpr int kL  = 2048;
constexpr int kM  = kB * kL; // 4096 rows total

typedef __attribute__((ext_vector_type(8))) short  bf8v;   // 8 bf16 (4 VGPR) MFMA frag
typedef __attribute__((ext_vector_type(4))) float  f4v;    // MFMA accumulator
typedef __attribute__((ext_vector_type(4))) unsigned short us4v;

#define MFMA_BF16 __builtin_amdgcn_mfma_f32_16x16x32_bf16

__device__ inline unsigned short f2bf(float f) {
    __hip_bfloat16 h = __float2bfloat16(f);
    return *(unsigned short*)&h;
}
__device__ inline float bf2f(unsigned short u) {
    __hip_bfloat16 h = *(__hip_bfloat16*)&u;
    return __bfloat162float(h);
}

// ---------------- split-convert: fp32 -> (hi, lo) bf16 ----------------
__global__ __launch_bounds__(256) void convert_split(
    const float* __restrict__ src, unsigned short* __restrict__ hi,
    unsigned short* __restrict__ lo, int n4)
{
    const int i = blockIdx.x * 256 + threadIdx.x;
    if (i >= n4) return;
    const float4 v = ((const float4*)src)[i];
    const float vv[4] = {v.x, v.y, v.z, v.w};
    us4v h, l;
    #pragma unroll
    for (int c = 0; c < 4; ++c) {
        h[c] = f2bf(vv[c]);
        l[c] = f2bf(vv[c] - bf2f(h[c]));
    }
    *(us4v*)&hi[(size_t)i * 4] = h;
    *(us4v*)&lo[(size_t)i * 4] = l;
}

// ---------------- LayerNorm -> split bf16 ----------------
__global__ __launch_bounds__(256) void ln_kernel(
    const float* __restrict__ x, const float* __restrict__ g,
    const float* __restrict__ beta, unsigned short* __restrict__ h_hi,
    unsigned short* __restrict__ h_lo)
{
    const int row = blockIdx.x;
    const int tid = threadIdx.x;
    const float4 v = ((const float4*)(x + (size_t)row * kD))[tid];
    float s  = v.x + v.y + v.z + v.w;
    float s2 = v.x*v.x + v.y*v.y + v.z*v.z + v.w*v.w;
    #pragma unroll
    for (int off = 32; off > 0; off >>= 1) {
        s  += __shfl_down(s, off);
        s2 += __shfl_down(s2, off);
    }
    __shared__ float wsum[4], wsum2[4];
    const int lane = tid & 63, wid = tid >> 6;
    if (lane == 0) { wsum[wid] = s; wsum2[wid] = s2; }
    __syncthreads();
    const float ts   = wsum[0] + wsum[1] + wsum[2] + wsum[3];
    const float ts2  = wsum2[0] + wsum2[1] + wsum2[2] + wsum2[3];
    const float mean = ts * (1.0f / kD);
    const float var  = ts2 * (1.0f / kD) - mean * mean;
    const float rstd = rsqrtf(var + 1e-5f);
    const float4 gv = ((const float4*)g)[tid];
    const float4 bv = ((const float4*)beta)[tid];
    float o[4];
    o[0] = (v.x - mean) * rstd * gv.x + bv.x;
    o[1] = (v.y - mean) * rstd * gv.y + bv.y;
    o[2] = (v.z - mean) * rstd * gv.z + bv.z;
    o[3] = (v.w - mean) * rstd * gv.w + bv.w;
    us4v h, l;
    #pragma unroll
    for (int c = 0; c < 4; ++c) {
        h[c] = f2bf(o[c]);
        l[c] = f2bf(o[c] - bf2f(h[c]));
    }
    *(us4v*)&h_hi[(size_t)row * kD + tid * 4] = h;
    *(us4v*)&h_lo[(size_t)row * kD + tid * 4] = l;
}

// ---------------- split-bf16 MFMA NT GEMM (unchanged from R4) ----------------
template<int MODE>
__global__ __launch_bounds__(256) void gemm_split(
    const unsigned short* __restrict__ Ahi, const unsigned short* __restrict__ Alo,
    const unsigned short* __restrict__ Bhi, const unsigned short* __restrict__ Blo,
    const float* __restrict__ bias, const float* __restrict__ resid,
    void* __restrict__ Cout, int N, int K)
{
    constexpr int BK = 32, PAD = 40;
    __shared__ unsigned short As[2][128][PAD];
    __shared__ unsigned short Bs[2][128][PAD];
    const int tid = threadIdx.x;
    const int l = tid & 63, w = tid >> 6;
    const int col16 = l & 15, grp = l >> 4;
    const int wr = (w >> 1) * 64, wc = (w & 1) * 64;
    const int row0 = blockIdx.y * 128, col0 = blockIdx.x * 128;
    f4v acc[4][4] = {};

    for (int k0 = 0; k0 < K; k0 += BK) {
        __syncthreads();
        #pragma unroll
        for (int t = 0; t < 2; ++t) {
            const int i = tid + t * 256;          // 512 slots of 8 elems
            const int r = i >> 2, c8 = (i & 3) * 8;
            const size_t ga = (size_t)(row0 + r) * K + k0 + c8;
            const size_t gb = (size_t)(col0 + r) * K + k0 + c8;
            *(bf8v*)&As[0][r][c8] = *(const bf8v*)&Ahi[ga];
            *(bf8v*)&As[1][r][c8] = *(const bf8v*)&Alo[ga];
            *(bf8v*)&Bs[0][r][c8] = *(const bf8v*)&Bhi[gb];
            *(bf8v*)&Bs[1][r][c8] = *(const bf8v*)&Blo[gb];
        }
        __syncthreads();
        bf8v ah[4], al[4], bh[4], bl[4];
        #pragma unroll
        for (int mi = 0; mi < 4; ++mi) {
            ah[mi] = *(bf8v*)&As[0][wr + mi*16 + col16][grp * 8];
            al[mi] = *(bf8v*)&As[1][wr + mi*16 + col16][grp * 8];
        }
        #pragma unroll
        for (int ni = 0; ni < 4; ++ni) {
            bh[ni] = *(bf8v*)&Bs[0][wc + ni*16 + col16][grp * 8];
            bl[ni] = *(bf8v*)&Bs[1][wc + ni*16 + col16][grp * 8];
        }
        #pragma unroll
        for (int mi = 0; mi < 4; ++mi)
            #pragma unroll
            for (int ni = 0; ni < 4; ++ni) {
                acc[mi][ni] = MFMA_BF16(ah[mi], bh[ni], acc[mi][ni], 0, 0, 0);
                acc[mi][ni] = MFMA_BF16(ah[mi], bl[ni], acc[mi][ni], 0, 0, 0);
                acc[mi][ni] = MFMA_BF16(al[mi], bh[ni], acc[mi][ni], 0, 0, 0);
            }
    }
    #pragma unroll
    for (int mi = 0; mi < 4; ++mi)
        #pragma unroll
        for (int ni = 0; ni < 4; ++ni) {
            const int gcol = col0 + wc + ni*16 + col16;
            const float bb = bias[gcol];
            #pragma unroll
            for (int rr = 0; rr < 4; ++rr) {
                const int grow = row0 + wr + mi*16 + grp*4 + rr;
                float o = acc[mi][ni][rr] + bb;
                if (MODE == 0) {
                    ((unsigned short*)Cout)[(size_t)grow * N + gcol] = f2bf(o);
                } else {
                    o += resid[(size_t)grow * N + gcol];
                    o = 0.5f * o * (1.0f + erff(o * 0.70710678118654752f));
                    ((float*)Cout)[(size_t)grow * N + gcol] = o;
                }
            }
        }
}

// ---------------- MFMA flash attention v2 ----------------
// Q in registers, packed-u32 P (hi|lo), __expf softmax, 35KB LDS -> 4 blocks/CU.
// grid = (32 bh, 32 qt'), qt = 31 - blockIdx.y (long tiles dispatch first).
__global__ __launch_bounds__(256, 4) void attn_mfma(
    const unsigned short* __restrict__ projb,
    unsigned short* __restrict__ heads_hi, unsigned short* __restrict__ heads_lo)
{
    __shared__ unsigned short Ks[64][72];
    __shared__ unsigned short Vt[64][72];
    __shared__ unsigned int   Ps32[4][16][68];  // (hi | lo<<16) packed P
    const int tid = threadIdx.x;
    const int l = tid & 63, w = tid >> 6;
    const int col16 = l & 15, grp = l >> 4;
    const int bh = blockIdx.x, b = bh >> 4, hh = bh & 15;
    const int qt = 31 - (int)blockIdx.y;      // load balance: big tiles first
    const int q0 = qt * 64;

    // Q rows are wave-private -> straight to registers (A-frag layout)
    const size_t qbase = (size_t)(b*kL + q0 + w*16 + col16) * 3072 + hh*64 + grp*8;
    bf8v aq[2];
    aq[0] = *(const bf8v*)&projb[qbase];
    aq[1] = *(const bf8v*)&projb[qbase + 32];

    f4v accO[4] = {};
    float m_r[4], l_r[4];
    #pragma unroll
    for (int r = 0; r < 4; ++r) { m_r[r] = -INFINITY; l_r[r] = 0.0f; }
    const int ntiles = qt + 1;

    for (int jt = 0; jt < ntiles; ++jt) {
        const int j0 = jt * 64;
        __syncthreads();   // prev tile done with Ks/Vt/Ps
        #pragma unroll
        for (int t = 0; t < 2; ++t) {
            const int i = tid + t * 256;
            const int r = i >> 3, c8 = (i & 7) * 8;
            const size_t base = (size_t)(b*kL + j0 + r) * 3072 + hh*64 + c8;
            *(bf8v*)&Ks[r][c8] = *(const bf8v*)&projb[base + 1024];
            const bf8v vv = *(const bf8v*)&projb[base + 2048];
            #pragma unroll
            for (int q = 0; q < 8; ++q)
                Vt[c8 + q][r] = ((const unsigned short*)&vv)[q];  // transpose V
        }
        __syncthreads();

        // S = Q K^T
        f4v accS[4] = {};
        #pragma unroll
        for (int kk = 0; kk < 2; ++kk)
            #pragma unroll
            for (int nj = 0; nj < 4; ++nj) {
                const bf8v bk = *(bf8v*)&Ks[nj*16 + col16][grp*8 + kk*32];
                accS[nj] = MFMA_BF16(aq[kk], bk, accS[nj], 0, 0, 0);
            }

        // scale + causal mask + wave-private online softmax (fast exp)
        const bool diag = (jt == qt);
        float p[4][4];  // [nj][r]
        float alpha[4];
        #pragma unroll
        for (int r = 0; r < 4; ++r) {
            const int q_local = w*16 + grp*4 + r;
            float sv[4];
            #pragma unroll
            for (int nj = 0; nj < 4; ++nj) {
                sv[nj] = accS[nj][r] * (1.0f / 32.0f);
                if (diag && (nj*16 + col16 > q_local)) sv[nj] = -3.125e7f; // (-1e9)/32
            }
            float pm = fmaxf(fmaxf(sv[0], sv[1]), fmaxf(sv[2], sv[3]));
            pm = fmaxf(pm, __shfl_xor(pm, 1));
            pm = fmaxf(pm, __shfl_xor(pm, 2));
            pm = fmaxf(pm, __shfl_xor(pm, 4));
            pm = fmaxf(pm, __shfl_xor(pm, 8));
            const float m_new = fmaxf(m_r[r], pm);
            alpha[r] = __expf(m_r[r] - m_new);
            m_r[r] = m_new;
            float ps = 0.0f;
            #pragma unroll
            for (int nj = 0; nj < 4; ++nj) {
                p[nj][r] = __expf(sv[nj] - m_new);
                ps += p[nj][r];
            }
            ps += __shfl_xor(ps, 1);
            ps += __shfl_xor(ps, 2);
            ps += __shfl_xor(ps, 4);
            ps += __shfl_xor(ps, 8);
            l_r[r] = l_r[r] * alpha[r] + ps;
        }
        #pragma unroll
        for (int nd = 0; nd < 4; ++nd)
            #pragma unroll
            for (int r = 0; r < 4; ++r)
                accO[nd][r] *= alpha[r];

        // P -> LDS, hi|lo packed in one u32 (16 b32 writes, conflict-free)
        #pragma unroll
        for (int nj = 0; nj < 4; ++nj)
            #pragma unroll
            for (int r = 0; r < 4; ++r) {
                const unsigned hi = f2bf(p[nj][r]);
                const unsigned lo = f2bf(p[nj][r] - bf2f((unsigned short)hi));
                Ps32[w][grp*4 + r][nj*16 + col16] = hi | (lo << 16);
            }
        asm volatile("s_waitcnt lgkmcnt(0)" ::: "memory"); // wave DS ops in order

        // O += (Phi + Plo) V
        #pragma unroll
        for (int js = 0; js < 2; ++js) {
            const uint4 pa0 = *(const uint4*)&Ps32[w][col16][js*32 + grp*8];
            const uint4 pa1 = *(const uint4*)&Ps32[w][col16][js*32 + grp*8 + 4];
            const unsigned pu[8] = {pa0.x, pa0.y, pa0.z, pa0.w,
                                    pa1.x, pa1.y, pa1.z, pa1.w};
            bf8v ph, pl;
            #pragma unroll
            for (int i = 0; i < 8; ++i) {
                ph[i] = (short)(pu[i] & 0xffffu);
                pl[i] = (short)(pu[i] >> 16);
            }
            #pragma unroll
            for (int nd = 0; nd < 4; ++nd) {
                const bf8v bv = *(bf8v*)&Vt[nd*16 + col16][grp*8 + js*32];
                accO[nd] = MFMA_BF16(ph, bv, accO[nd], 0, 0, 0);
                accO[nd] = MFMA_BF16(pl, bv, accO[nd], 0, 0, 0);
            }
        }
    }
    // epilogue: heads split bf16
    #pragma unroll
    for (int nd = 0; nd < 4; ++nd)
        #pragma unroll
        for (int r = 0; r < 4; ++r) {
            const float o = accO[nd][r] / l_r[r];
            const unsigned short hi = f2bf(o);
            const unsigned short lo = f2bf(o - bf2f(hi));
            const size_t idx = (size_t)(b*kL + q0 + w*16 + grp*4 + r) * kD
                             + hh*64 + nd*16 + col16;
            heads_hi[idx] = hi;
            heads_lo[idx] = lo;
        }
}

extern "C" void kernel_launch(void* const* d_in, const int* in_sizes, int n_in,
                              void* d_out, int out_size, void* d_ws, size_t ws_size,
                              hipStream_t stream)
{
    const float* x    = (const float*)d_in[0];
    const float* mask = (const float*)d_in[1];
    const float* wx_w = (const float*)d_in[2];
    const float* wx_b = (const float*)d_in[3];
    const float* wo_w = (const float*)d_in[4];
    const float* wo_b = (const float*)d_in[5];
    const float* ln_g = (const float*)d_in[6];
    const float* ln_b = (const float*)d_in[7];
    float* out = (float*)d_out;

    // ws layout (bf16 ushort arrays):
    // h_hi 8MB | h_lo 8MB | wxhi 6 | wxlo 6 | wohi 2 | wolo 2 | projb 24 | hd_hi 8 | hd_lo 8  = 72MB
    unsigned short* h_hi  = (unsigned short*)d_ws;
    unsigned short* h_lo  = h_hi  + (size_t)kM * kD;
    unsigned short* wxhi  = h_lo  + (size_t)kM * kD;
    unsigned short* wxlo  = wxhi  + (size_t)3 * kD * kD;
    unsigned short* wohi  = wxlo  + (size_t)3 * kD * kD;
    unsigned short* wolo  = wohi  + (size_t)kD * kD;
    unsigned short* projb = wolo  + (size_t)kD * kD;
    unsigned short* hd_hi = projb + (size_t)kM * 3 * kD;
    unsigned short* hd_lo = hd_hi + (size_t)kM * kD;

    convert_split<<<(3*kD*kD/4 + 255)/256, 256, 0, stream>>>(wx_w, wxhi, wxlo, 3*kD*kD/4);
    convert_split<<<(kD*kD/4 + 255)/256, 256, 0, stream>>>(wo_w, wohi, wolo, kD*kD/4);
    ln_kernel<<<kM, 256, 0, stream>>>(x, ln_g, ln_b, h_hi, h_lo);
    gemm_split<0><<<dim3(3*kD/128, kM/128), 256, 0, stream>>>(
        h_hi, h_lo, wxhi, wxlo, wx_b, nullptr, projb, 3*kD, kD);
    attn_mfma<<<dim3(kB*16, kL/64), 256, 0, stream>>>(projb, hd_hi, hd_lo);
    gemm_split<1><<<dim3(kD/128, kM/128), 256, 0, stream>>>(
        hd_hi, hd_lo, wohi, wolo, wo_b, x, out, kD, kD);
    hipMemcpyAsync(out + (size_t)kM * kD, mask, (size_t)kL * kL * sizeof(float),
                   hipMemcpyDeviceToDevice, stream);
}

// Round 6
// 314.159 us; speedup vs baseline: 5.5152x; 1.1596x over previous
//
#include <hip/hip_runtime.h>
#include <hip/hip_bf16.h>
#include <math.h>

constexpr int kD  = 1024;
constexpr int kB  = 2;
constexpr int kL  = 2048;
constexpr int kM  = kB * kL; // 4096 rows total

typedef __attribute__((ext_vector_type(8))) short  bf8v;   // 8 bf16 (4 VGPR) MFMA frag
typedef __attribute__((ext_vector_type(4))) float  f4v;    // MFMA accumulator
typedef __attribute__((ext_vector_type(4))) unsigned short us4v;

#define MFMA_BF16 __builtin_amdgcn_mfma_f32_16x16x32_bf16

__device__ inline unsigned short f2bf(float f) {
    __hip_bfloat16 h = __float2bfloat16(f);
    return *(unsigned short*)&h;
}
__device__ inline float bf2f(unsigned short u) {
    __hip_bfloat16 h = *(__hip_bfloat16*)&u;
    return __bfloat162float(h);
}
// async global->LDS, 16B per lane; lds dest = wave-uniform base + lane*16
__device__ inline void gload16(const void* g, void* l) {
    __builtin_amdgcn_global_load_lds(
        (const __attribute__((address_space(1))) void*)g,
        (__attribute__((address_space(3))) void*)l, 16, 0, 0);
}

// ---------------- split-convert: fp32 -> (hi, lo) bf16 ----------------
__global__ __launch_bounds__(256) void convert_split(
    const float* __restrict__ src, unsigned short* __restrict__ hi,
    unsigned short* __restrict__ lo, int n4)
{
    const int i = blockIdx.x * 256 + threadIdx.x;
    if (i >= n4) return;
    const float4 v = ((const float4*)src)[i];
    const float vv[4] = {v.x, v.y, v.z, v.w};
    us4v h, l;
    #pragma unroll
    for (int c = 0; c < 4; ++c) {
        h[c] = f2bf(vv[c]);
        l[c] = f2bf(vv[c] - bf2f(h[c]));
    }
    *(us4v*)&hi[(size_t)i * 4] = h;
    *(us4v*)&lo[(size_t)i * 4] = l;
}

// ---------------- LayerNorm -> split bf16 ----------------
__global__ __launch_bounds__(256) void ln_kernel(
    const float* __restrict__ x, const float* __restrict__ g,
    const float* __restrict__ beta, unsigned short* __restrict__ h_hi,
    unsigned short* __restrict__ h_lo)
{
    const int row = blockIdx.x;
    const int tid = threadIdx.x;
    const float4 v = ((const float4*)(x + (size_t)row * kD))[tid];
    float s  = v.x + v.y + v.z + v.w;
    float s2 = v.x*v.x + v.y*v.y + v.z*v.z + v.w*v.w;
    #pragma unroll
    for (int off = 32; off > 0; off >>= 1) {
        s  += __shfl_down(s, off);
        s2 += __shfl_down(s2, off);
    }
    __shared__ float wsum[4], wsum2[4];
    const int lane = tid & 63, wid = tid >> 6;
    if (lane == 0) { wsum[wid] = s; wsum2[wid] = s2; }
    __syncthreads();
    const float ts   = wsum[0] + wsum[1] + wsum[2] + wsum[3];
    const float ts2  = wsum2[0] + wsum2[1] + wsum2[2] + wsum2[3];
    const float mean = ts * (1.0f / kD);
    const float var  = ts2 * (1.0f / kD) - mean * mean;
    const float rstd = rsqrtf(var + 1e-5f);
    const float4 gv = ((const float4*)g)[tid];
    const float4 bv = ((const float4*)beta)[tid];
    float o[4];
    o[0] = (v.x - mean) * rstd * gv.x + bv.x;
    o[1] = (v.y - mean) * rstd * gv.y + bv.y;
    o[2] = (v.z - mean) * rstd * gv.z + bv.z;
    o[3] = (v.w - mean) * rstd * gv.w + bv.w;
    us4v h, l;
    #pragma unroll
    for (int c = 0; c < 4; ++c) {
        h[c] = f2bf(o[c]);
        l[c] = f2bf(o[c] - bf2f(h[c]));
    }
    *(us4v*)&h_hi[(size_t)row * kD + tid * 4] = h;
    *(us4v*)&h_lo[(size_t)row * kD + tid * 4] = l;
}

// ---------------- split-bf16 MFMA NT GEMM, global_load_lds staging ----------
// MODE 0 (QKV): acc = AhBh + AhBl + AlBh; out bf16: Q cols prescaled 1/32 ->
//               projb (cols<2048), V cols transposed -> vT[b*16+h][64][2048].
// MODE 1 (WO):  acc = AhBh + AhBl (A single); out fp32 = gelu(resid+acc+bias).
// LDS linear [128][32] per array; k-chunk XOR-swizzle: pos = chunk ^ ((row>>1)&3)
// (pre-swizzled global source + same XOR on read; dest stays linear).
template<int MODE>
__global__ __launch_bounds__(256, 3) void gemm_split(
    const unsigned short* __restrict__ Ahi, const unsigned short* __restrict__ Alo,
    const unsigned short* __restrict__ Bhi, const unsigned short* __restrict__ Blo,
    const float* __restrict__ bias, const float* __restrict__ resid,
    unsigned short* __restrict__ outb, unsigned short* __restrict__ vT,
    float* __restrict__ outf, int N, int K)
{
    constexpr int NARR = (MODE == 0) ? 4 : 3;
    __shared__ unsigned short S[NARR][128][32];
    const int tid = threadIdx.x;
    const int l = tid & 63, w = tid >> 6;
    const int col16 = l & 15, grp = l >> 4;
    const int wr = (w >> 1) * 64, wc = (w & 1) * 64;
    const int row0 = blockIdx.y * 128, col0 = blockIdx.x * 128;
    // staging geometry: lane -> LDS (row sr, chunk l&3); source chunk swizzled
    const int sr = l >> 2;
    const int sc8 = ((l & 3) ^ ((sr >> 1) & 3)) * 8;
    const unsigned short* gb;
    int rb;
    if (MODE == 0) {
        gb = (w == 0) ? Ahi : (w == 1) ? Alo : (w == 2) ? Bhi : Blo;
        rb = (w < 2) ? row0 : col0;
    } else {
        gb = (w == 0) ? Ahi : (w == 1) ? Bhi : Blo;
        rb = (w == 0) ? row0 : col0;
    }
    const bool do_stage = (MODE == 0) || (w < 3);
    const int pos8 = (grp ^ ((col16 >> 1) & 3)) * 8;   // read-side swizzle
    f4v acc[4][4] = {};

    for (int k0 = 0; k0 < K; k0 += 32) {
        __syncthreads();
        if (do_stage) {
            #pragma unroll
            for (int t = 0; t < 8; ++t)
                gload16(gb + (size_t)(rb + t*16 + sr) * K + k0 + sc8,
                        &S[w][t*16][0]);
        }
        __syncthreads();   // compiler drains vmcnt(0) here
        bf8v ah[4], al[4], bh[4], bl[4];
        #pragma unroll
        for (int mi = 0; mi < 4; ++mi) {
            ah[mi] = *(bf8v*)&S[0][wr + mi*16 + col16][pos8];
            if (MODE == 0) al[mi] = *(bf8v*)&S[1][wr + mi*16 + col16][pos8];
        }
        #pragma unroll
        for (int ni = 0; ni < 4; ++ni) {
            bh[ni] = *(bf8v*)&S[(MODE == 0) ? 2 : 1][wc + ni*16 + col16][pos8];
            bl[ni] = *(bf8v*)&S[(MODE == 0) ? 3 : 2][wc + ni*16 + col16][pos8];
        }
        #pragma unroll
        for (int mi = 0; mi < 4; ++mi)
            #pragma unroll
            for (int ni = 0; ni < 4; ++ni) {
                acc[mi][ni] = MFMA_BF16(ah[mi], bh[ni], acc[mi][ni], 0, 0, 0);
                acc[mi][ni] = MFMA_BF16(ah[mi], bl[ni], acc[mi][ni], 0, 0, 0);
                if (MODE == 0)
                    acc[mi][ni] = MFMA_BF16(al[mi], bh[ni], acc[mi][ni], 0, 0, 0);
            }
    }
    #pragma unroll
    for (int mi = 0; mi < 4; ++mi)
        #pragma unroll
        for (int ni = 0; ni < 4; ++ni) {
            const int gcol = col0 + wc + ni*16 + col16;
            const float bb = bias[gcol];
            #pragma unroll
            for (int rr = 0; rr < 4; ++rr) {
                const int grow = row0 + wr + mi*16 + grp*4 + rr;
                float o = acc[mi][ni][rr] + bb;
                if (MODE == 0) {
                    if (gcol < 2048) {
                        if (gcol < 1024) o *= (1.0f / 32.0f);  // fold softmax scale into Q
                        outb[(size_t)grow * 3072 + gcol] = f2bf(o);
                    } else {
                        const int dg = gcol - 2048;
                        vT[((size_t)((grow >> 11) * 16 + (dg >> 6)) * 64 + (dg & 63)) * 2048
                           + (grow & 2047)] = f2bf(o);
                    }
                } else {
                    o += resid[(size_t)grow * N + gcol];
                    o = 0.5f * o * (1.0f + erff(o * 0.70710678118654752f));
                    outf[(size_t)grow * N + gcol] = o;
                }
            }
        }
}

// ---------------- MFMA flash attention v3 ----------------
// K from projb, V from pre-transposed vT; both staged via global_load_lds into
// linear [64][64] LDS with chunk swizzle pos = chunk ^ (row&7). Q in registers
// (prescaled). Wave-private softmax + packed-u32 P. 33KB LDS -> 4 blocks/CU.
__global__ __launch_bounds__(256, 4) void attn_mfma(
    const unsigned short* __restrict__ projb, const unsigned short* __restrict__ vT,
    unsigned short* __restrict__ heads_hi)
{
    __shared__ unsigned short Ks[64 * 64];
    __shared__ unsigned short Vs[64 * 64];
    __shared__ unsigned int   Ps32[4][16][68];  // (hi | lo<<16) packed P
    const int tid = threadIdx.x;
    const int l = tid & 63, w = tid >> 6;
    const int col16 = l & 15, grp = l >> 4;
    const int bh = blockIdx.x, b = bh >> 4, hh = bh & 15;
    const int qt = 31 - (int)blockIdx.y;      // big tiles dispatch first
    const int q0 = qt * 64;
    const unsigned short* vTh = vT + (size_t)bh * 64 * 2048;

    // staging lane geometry: 1KB per gload = 8 rows x 64 cols
    const int r8 = l >> 3;
    const int sc8 = ((l & 7) ^ r8) * 8;       // swizzled source col
    const int isV = w >> 1;
    const int t0 = (w & 1) * 4;
    const int sw7 = col16 & 7;                 // read-side swizzle key

    // Q A-frags straight from global (already 1/32-prescaled by GEMM epilogue)
    const size_t qbase = (size_t)(b*kL + q0 + w*16 + col16) * 3072 + hh*64 + grp*8;
    bf8v aq[2];
    aq[0] = *(const bf8v*)&projb[qbase];
    aq[1] = *(const bf8v*)&projb[qbase + 32];

    f4v accO[4] = {};
    float m_r[4], l_r[4];
    #pragma unroll
    for (int r = 0; r < 4; ++r) { m_r[r] = -INFINITY; l_r[r] = 0.0f; }

    for (int jt = 0; jt <= qt; ++jt) {
        const int j0 = jt * 64;
        __syncthreads();   // prev tile's reads done before DMA overwrites
        #pragma unroll
        for (int t2 = 0; t2 < 4; ++t2) {
            const int t = t0 + t2;
            if (isV)
                gload16(&vTh[(size_t)(t*8 + r8) * 2048 + j0 + sc8], &Vs[t*8*64]);
            else
                gload16(&projb[(size_t)(b*kL + j0 + t*8 + r8) * 3072 + hh*64 + 1024 + sc8],
                        &Ks[t*8*64]);
        }
        __syncthreads();   // vmcnt(0) drain -> tiles ready

        // S = (Q/32) K^T
        f4v accS[4] = {};
        #pragma unroll
        for (int kk = 0; kk < 2; ++kk)
            #pragma unroll
            for (int nj = 0; nj < 4; ++nj) {
                const int row = nj*16 + col16;
                const bf8v bk = *(bf8v*)&Ks[row*64 + (((grp + kk*4) ^ sw7) * 8)];
                accS[nj] = MFMA_BF16(aq[kk], bk, accS[nj], 0, 0, 0);
            }

        // causal mask + wave-private online softmax
        const bool diag = (jt == qt);
        float p[4][4];  // [nj][r]
        float alpha[4];
        #pragma unroll
        for (int r = 0; r < 4; ++r) {
            const int q_local = w*16 + grp*4 + r;
            float sv[4];
            #pragma unroll
            for (int nj = 0; nj < 4; ++nj) {
                sv[nj] = accS[nj][r];
                if (diag && (nj*16 + col16 > q_local)) sv[nj] = -1e9f;
            }
            float pm = fmaxf(fmaxf(sv[0], sv[1]), fmaxf(sv[2], sv[3]));
            pm = fmaxf(pm, __shfl_xor(pm, 1));
            pm = fmaxf(pm, __shfl_xor(pm, 2));
            pm = fmaxf(pm, __shfl_xor(pm, 4));
            pm = fmaxf(pm, __shfl_xor(pm, 8));
            const float m_new = fmaxf(m_r[r], pm);
            alpha[r] = __expf(m_r[r] - m_new);
            m_r[r] = m_new;
            float ps = 0.0f;
            #pragma unroll
            for (int nj = 0; nj < 4; ++nj) {
                p[nj][r] = __expf(sv[nj] - m_new);
                ps += p[nj][r];
            }
            ps += __shfl_xor(ps, 1);
            ps += __shfl_xor(ps, 2);
            ps += __shfl_xor(ps, 4);
            ps += __shfl_xor(ps, 8);
            l_r[r] = l_r[r] * alpha[r] + ps;
        }
        #pragma unroll
        for (int nd = 0; nd < 4; ++nd)
            #pragma unroll
            for (int r = 0; r < 4; ++r)
                accO[nd][r] *= alpha[r];

        // P -> LDS, hi|lo packed u32 (conflict-free)
        #pragma unroll
        for (int nj = 0; nj < 4; ++nj)
            #pragma unroll
            for (int r = 0; r < 4; ++r) {
                const unsigned hi = f2bf(p[nj][r]);
                const unsigned lo = f2bf(p[nj][r] - bf2f((unsigned short)hi));
                Ps32[w][grp*4 + r][nj*16 + col16] = hi | (lo << 16);
            }
        asm volatile("s_waitcnt lgkmcnt(0)" ::: "memory"); // wave DS ops in order

        // O += (Phi + Plo) V
        #pragma unroll
        for (int js = 0; js < 2; ++js) {
            const uint4 pa0 = *(const uint4*)&Ps32[w][col16][js*32 + grp*8];
            const uint4 pa1 = *(const uint4*)&Ps32[w][col16][js*32 + grp*8 + 4];
            const unsigned pu[8] = {pa0.x, pa0.y, pa0.z, pa0.w,
                                    pa1.x, pa1.y, pa1.z, pa1.w};
            bf8v ph, pl;
            #pragma unroll
            for (int i = 0; i < 8; ++i) {
                ph[i] = (short)(pu[i] & 0xffffu);
                pl[i] = (short)(pu[i] >> 16);
            }
            #pragma unroll
            for (int nd = 0; nd < 4; ++nd) {
                const int row = nd*16 + col16;
                const bf8v bv = *(bf8v*)&Vs[row*64 + (((grp + js*4) ^ sw7) * 8)];
                accO[nd] = MFMA_BF16(ph, bv, accO[nd], 0, 0, 0);
                accO[nd] = MFMA_BF16(pl, bv, accO[nd], 0, 0, 0);
            }
        }
    }
    // epilogue: heads bf16 (single round; lo-term dropped in WO GEMM)
    #pragma unroll
    for (int nd = 0; nd < 4; ++nd)
        #pragma unroll
        for (int r = 0; r < 4; ++r) {
            const float o = accO[nd][r] / l_r[r];
            heads_hi[(size_t)(b*kL + q0 + w*16 + grp*4 + r) * kD
                     + hh*64 + nd*16 + col16] = f2bf(o);
        }
}

extern "C" void kernel_launch(void* const* d_in, const int* in_sizes, int n_in,
                              void* d_out, int out_size, void* d_ws, size_t ws_size,
                              hipStream_t stream)
{
    const float* x    = (const float*)d_in[0];
    const float* mask = (const float*)d_in[1];
    const float* wx_w = (const float*)d_in[2];
    const float* wx_b = (const float*)d_in[3];
    const float* wo_w = (const float*)d_in[4];
    const float* wo_b = (const float*)d_in[5];
    const float* ln_g = (const float*)d_in[6];
    const float* ln_b = (const float*)d_in[7];
    float* out = (float*)d_out;

    // ws (ushort elems): h_hi 4M | h_lo 4M | wxhi 3M | wxlo 3M | wohi 1M | wolo 1M
    //                    | projb 12M | hd_hi 4M | vT 4M   = 36M elems = 72MB
    unsigned short* h_hi  = (unsigned short*)d_ws;
    unsigned short* h_lo  = h_hi  + (size_t)kM * kD;
    unsigned short* wxhi  = h_lo  + (size_t)kM * kD;
    unsigned short* wxlo  = wxhi  + (size_t)3 * kD * kD;
    unsigned short* wohi  = wxlo  + (size_t)3 * kD * kD;
    unsigned short* wolo  = wohi  + (size_t)kD * kD;
    unsigned short* projb = wolo  + (size_t)kD * kD;
    unsigned short* hd_hi = projb + (size_t)kM * 3 * kD;
    unsigned short* vT    = hd_hi + (size_t)kM * kD;

    convert_split<<<(3*kD*kD/4 + 255)/256, 256, 0, stream>>>(wx_w, wxhi, wxlo, 3*kD*kD/4);
    convert_split<<<(kD*kD/4 + 255)/256, 256, 0, stream>>>(wo_w, wohi, wolo, kD*kD/4);
    ln_kernel<<<kM, 256, 0, stream>>>(x, ln_g, ln_b, h_hi, h_lo);
    gemm_split<0><<<dim3(3*kD/128, kM/128), 256, 0, stream>>>(
        h_hi, h_lo, wxhi, wxlo, wx_b, nullptr, projb, vT, nullptr, 3*kD, kD);
    attn_mfma<<<dim3(kB*16, kL/64), 256, 0, stream>>>(projb, vT, hd_hi);
    gemm_split<1><<<dim3(kD/128, kM/128), 256, 0, stream>>>(
        hd_hi, nullptr, wohi, wolo, wo_b, x, nullptr, nullptr, out, kD, kD);
    hipMemcpyAsync(out + (size_t)kM * kD, mask, (size_t)kL * kL * sizeof(float),
                   hipMemcpyDeviceToDevice, stream);
}